// Round 8
// baseline (6138.986 us; speedup 1.0000x reference)
//
#include <hip/hip_runtime.h>
#include <hip/hip_fp16.h>

typedef _Float16 f16;
typedef _Float16 f16x8 __attribute__((ext_vector_type(8)));
typedef _Float16 f16x4 __attribute__((ext_vector_type(4)));
typedef float f32x4v __attribute__((ext_vector_type(4)));
typedef unsigned long long u64;

#define S_LEN 1024
#define NS 512
#define NV 32000
#define NCAND 32      // election candidate blocks (pigeonhole: some XCD gets 4)
#define SENT 0x7C007C007C007C00ULL   // 4x f16 +inf: unreachable for tanh output
#define FUSED_LDS 98304              // >80KB -> exactly 1 block/CU

#define MFMA16(a, b, c) __builtin_amdgcn_mfma_f32_16x16x32_f16((a), (b), (c), 0, 0, 0)

// ---------------------------------------------------------------------------
// ws layout:
//   u16   : [1024][512][4] f16  at 0      (4 MB)   u[s][n][b]  (batch-packed)
//   Xllc  : u64[1024][512]      at 4 MB   (4 MB)   LLC-visible state record
//   Xl    : u64[1024][512]      at 8 MB   (4 MB)   same-XCD L2 exchange
//   bT16  : [512][512]     f16  at 12 MB  (512 KB)
//   ctrl  : u32[16]             at 12.5MB          per-XCD counters + leader
// ---------------------------------------------------------------------------

__global__ __launch_bounds__(256) void transpose512_f16_kernel(
        const float* __restrict__ src, f16* __restrict__ dstT,
        u64* __restrict__ Xllc, u64* __restrict__ Xl,
        unsigned* __restrict__ ctrl) {
    int idx = blockIdx.x * 256 + threadIdx.x;   // 0..262143
    Xllc[idx] = SENT;
    Xllc[idx + 262144] = SENT;
    Xl[idx] = SENT;
    Xl[idx + 262144] = SENT;
    if (idx < 8) ctrl[idx] = 0;                 // per-XCD member counters
    if (idx == 8) ctrl[8] = 0xFFFFFFFFu;        // leader = none
    int r = idx >> 9;
    int c = idx & 511;
    dstT[c * 512 + r] = (f16)src[idx];
}

// ---------------------------------------------------------------------------
// embed + input projection: u[m][n] = sum_e emb[x[m]][e] * b[e][n], m = s*4+b
// ---------------------------------------------------------------------------
__global__ __launch_bounds__(256) void embu_kernel(
        const int* __restrict__ x, const float* __restrict__ emb,
        const f16* __restrict__ bT, f16* __restrict__ u16) {
    __shared__ f16 embA[64 * 40];
    __shared__ f16 Bt[512 * 40];
    __shared__ int xi[64];

    int t = threadIdx.x;
    int wg = blockIdx.x;
    if (t < 64) {
        int m = wg * 64 + t;
        int bb = m & 3, ss = m >> 2;
        xi[t] = x[bb * S_LEN + ss];
    }
    __syncthreads();

    int wv = t >> 6, l = t & 63, lr = l & 15, lg = l >> 4;

    f32x4v acc[32];
#pragma unroll
    for (int i = 0; i < 32; i++) acc[i] = (f32x4v){0.f, 0.f, 0.f, 0.f};

    for (int kc = 0; kc < 512; kc += 32) {
        __syncthreads();
        {
            int tk = t >> 2, c0 = (t & 3) * 8;
            const float* src = emb + (size_t)xi[tk] * NS + kc + c0;
            float4 v0 = *(const float4*)src;
            float4 v1 = *(const float4*)(src + 4);
            f16x8 h;
            h[0] = (f16)v0.x; h[1] = (f16)v0.y; h[2] = (f16)v0.z; h[3] = (f16)v0.w;
            h[4] = (f16)v1.x; h[5] = (f16)v1.y; h[6] = (f16)v1.z; h[7] = (f16)v1.w;
            *(f16x8*)&embA[tk * 40 + c0] = h;
        }
        {
            int c0 = (t & 3) * 8;
            int n0 = t >> 2;
#pragma unroll
            for (int rr = 0; rr < 8; rr++) {
                int n = rr * 64 + n0;
                f16x8 v = *(const f16x8*)&bT[n * 512 + kc + c0];
                *(f16x8*)&Bt[n * 40 + c0] = v;
            }
        }
        __syncthreads();

        f16x8 af = *(const f16x8*)&embA[(wv * 16 + lr) * 40 + 8 * lg];
#pragma unroll
        for (int vt = 0; vt < 32; vt++) {
            f16x8 bf = *(const f16x8*)&Bt[(vt * 16 + lr) * 40 + 8 * lg];
            acc[vt] = MFMA16(af, bf, acc[vt]);
        }
    }

    int m0 = wg * 64 + wv * 16 + 4 * lg;
    int ss = m0 >> 2;
#pragma unroll
    for (int vt = 0; vt < 32; vt++) {
        int n = vt * 16 + lr;
        f16x4 h;
#pragma unroll
        for (int i = 0; i < 4; i++) h[i] = (f16)acc[vt][i];
        *(f16x4*)&u16[((size_t)ss * NS + n) * 4] = h;
    }
}

// ---------------------------------------------------------------------------
// FUSED scan + readout.
//   blocks 0..31    : election candidates; 4 co-XCD winners run the scan,
//                     exchanging state via their SHARED L2 (plain store +
//                     sc0-only loads), with LLC fallback for hang-safety.
//   blocks 32..4031 : readout tiles (canary gate + per-element sentinel poll)
// ---------------------------------------------------------------------------
__global__ __launch_bounds__(512) void fused_kernel(
        const float* __restrict__ a, const f16* __restrict__ u16,
        const float* __restrict__ cw, const float* __restrict__ cb,
        u64* __restrict__ Xllc, u64* __restrict__ Xl,
        unsigned* __restrict__ ctrl, float* __restrict__ out) {
    extern __shared__ char smem[];
    int t = threadIdx.x;
    int bid = blockIdx.x;
    int w = t >> 6, l = t & 63, lr = l & 15, lg = l >> 4;

    if (bid < NCAND) {
        // ---------- election: find 4 blocks sharing one XCD ----------
        __shared__ unsigned rank_sh;
        if (t == 0) {
            unsigned xcd;
            asm volatile("s_getreg_b32 %0, hwreg(HW_REG_XCC_ID)" : "=s"(xcd));
            xcd &= 7;
            unsigned slot = atomicAdd(&ctrl[xcd], 1u);
            unsigned rank = 0xFFFFFFFFu;
            if (slot < 4) {
                if (slot == 3) atomicCAS(&ctrl[8], 0xFFFFFFFFu, xcd);
                unsigned ldr;
                do {
                    ldr = __hip_atomic_load(&ctrl[8], __ATOMIC_RELAXED,
                                            __HIP_MEMORY_SCOPE_AGENT);
                } while (ldr == 0xFFFFFFFFu);
                if (ldr == xcd) rank = slot;
            }
            rank_sh = rank;
        }
        __syncthreads();
        unsigned rank = rank_sh;
        if (rank == 0xFFFFFFFFu) return;     // loser: free this CU

        // ================= scan (4 co-XCD workers) =================
        f16* Sb = (f16*)smem;                // [2][4][544] f16
        int r = (int)rank;
        int col = r * 128 + w * 16 + lr;

        int gcol = -1;
        if (w < 6) {
            int cwk = w + (w >= 2 * r ? 2 : 0);   // skip own chunks {2r,2r+1}
            gcol = cwk * 64 + l;
        }

        for (int i = t; i < 2 * 4 * 544; i += 512) Sb[i] = (f16)0.f;

        f16x8 afr[16];
#pragma unroll
        for (int ks = 0; ks < 16; ks++) {
            f16x8 h;
#pragma unroll
            for (int j = 0; j < 8; j++)
                h[j] = (f16)a[(size_t)(ks * 32 + 8 * lg + j) * NS + col];
            afr[ks] = h;
        }

        f16x4 upf = *(const f16x4*)&u16[(size_t)col * 4];

        __syncthreads();

#pragma unroll 1
        for (int s = 0; s < S_LEN; s++) {
            int cur = s & 1, nxt = cur ^ 1;

            f32x4v acca, accb;
            acca[0] = (float)upf[0]; acca[1] = (float)upf[1];
            acca[2] = (float)upf[2]; acca[3] = (float)upf[3];
            accb = (f32x4v){0.f, 0.f, 0.f, 0.f};

            {
                int sn = (s + 1 < S_LEN) ? s + 1 : S_LEN - 1;
                upf = *(const f16x4*)&u16[((size_t)sn * NS + col) * 4];
            }

            const char* sb = (const char*)Sb + cur * 4352 +
                             (lr & 3) * 1088 + lg * 16;
#pragma unroll
            for (int ks = 0; ks < 16; ks += 2) {
                f16x8 s0 = *(const f16x8*)(sb + ks * 64);
                f16x8 s1 = *(const f16x8*)(sb + ks * 64 + 64);
                acca = MFMA16(s0, afr[ks], acca);
                accb = MFMA16(s1, afr[ks + 1], accb);
            }

            // tanh + publish: L2 store (peers) + LLC store (readout) + LDS
            if (lg == 0) {
                union { u64 u; f16 h[4]; } pk;
#pragma unroll
                for (int i = 0; i < 4; i++) {
                    float y = acca[i] + accb[i];
                    float e = __expf(2.0f * y);
                    float rc = __builtin_amdgcn_rcpf(e + 1.0f);
                    y = __builtin_fmaf(-2.0f, rc, 1.0f);   // tanh
                    pk.h[i] = (f16)y;
                }
                u64* apl = &Xl[(size_t)s * NS + col];
                asm volatile("global_store_dwordx2 %0, %1, off"
                             :: "v"(apl), "v"(pk.u) : "memory");
                __hip_atomic_store(&Xllc[(size_t)s * NS + col], pk.u,
                                   __ATOMIC_RELAXED, __HIP_MEMORY_SCOPE_AGENT);
#pragma unroll
                for (int i = 0; i < 4; i++)
                    Sb[nxt * 2176 + i * 544 + col] = pk.h[i];
            }

            if (s == S_LEN - 1) break;

            // gather remote cols: poll own-XCD L2 (sc0); LLC fallback for
            // hang-safety every 16 misses
            if (w < 6) {
                const u64* apL = &Xl[(size_t)s * NS + gcol];
                const u64* apG = &Xllc[(size_t)s * NS + gcol];
                u64 v;
                int it = 0;
                for (;;) {
                    asm volatile("global_load_dwordx2 %0, %1, off sc0\n\t"
                                 "s_waitcnt vmcnt(0)"
                                 : "=v"(v) : "v"(apL) : "memory");
                    if (v != SENT) break;
                    if ((++it & 15) == 0) {
                        v = __hip_atomic_load(apG, __ATOMIC_RELAXED,
                                              __HIP_MEMORY_SCOPE_AGENT);
                        if (v != SENT) break;
                    }
                }
                union { u64 u; f16 h[4]; } pk;
                pk.u = v;
#pragma unroll
                for (int i = 0; i < 4; i++)
                    Sb[nxt * 2176 + i * 544 + gcol] = pk.h[i];
            }

            asm volatile("s_waitcnt lgkmcnt(0)" ::: "memory");
            __builtin_amdgcn_s_barrier();
            __builtin_amdgcn_sched_barrier(0);
        }
        return;
    }

    // ================= readout =================
    f16* Ast = (f16*)smem;                 // [256][72]
    f16* Bw = (f16*)(smem + 256 * 72 * 2); // [128][72]

    int idx = bid - NCAND;
    int bm = idx / 250;      // bm-major: early blocks handle early s
    int bn = idx % 250;
    int s0 = bm * 64;

    if (t == 0) {
        int sc = (bm == 15) ? (S_LEN - 1) : (s0 + 64);
        while (__hip_atomic_load(&Xllc[(size_t)sc * NS], __ATOMIC_RELAXED,
                                 __HIP_MEMORY_SCOPE_AGENT) == SENT)
            __builtin_amdgcn_s_sleep(16);
    }
    __syncthreads();

    int wr = w >> 1, wc = w & 1;

    f32x4v acc[4][4];
#pragma unroll
    for (int i = 0; i < 4; i++)
#pragma unroll
        for (int j = 0; j < 4; j++) acc[i][j] = (f32x4v){0.f, 0.f, 0.f, 0.f};

    for (int kc = 0; kc < 512; kc += 64) {
        __syncthreads();
        // stage A from Xllc: 64 s x 64 cols of u64; per-element sentinel poll
        {
            int srel = t >> 3;
            int ck = (t & 7) * 8;
            const u64* xs = &Xllc[(size_t)(s0 + srel) * NS + kc + ck];
            u64 v[8];
#pragma unroll
            for (int j = 0; j < 8; j++)
                v[j] = __hip_atomic_load(&xs[j], __ATOMIC_RELAXED,
                                         __HIP_MEMORY_SCOPE_AGENT);
#pragma unroll
            for (int j = 0; j < 8; j++)
                while (v[j] == SENT)
                    v[j] = __hip_atomic_load(&xs[j], __ATOMIC_RELAXED,
                                             __HIP_MEMORY_SCOPE_AGENT);
#pragma unroll
            for (int j = 0; j < 8; j++) {
                union { u64 u; f16 h[4]; } pk;
                pk.u = v[j];
#pragma unroll
                for (int b = 0; b < 4; b++)
                    Ast[(srel * 4 + b) * 72 + ck + j] = pk.h[b];
            }
        }
#pragma unroll
        for (int q = 0; q < 4; q++) {
            int i2 = q * 512 + t;
            int row = i2 >> 4;
            int c0 = (i2 & 15) * 4;
            float4 v = *(const float4*)&cw[(size_t)(bn * 128 + row) * NS + kc + c0];
            f16x4 h;
            h[0] = (f16)v.x; h[1] = (f16)v.y; h[2] = (f16)v.z; h[3] = (f16)v.w;
            *(f16x4*)&Bw[row * 72 + c0] = h;
        }
        __syncthreads();

#pragma unroll
        for (int ks = 0; ks < 2; ks++) {
            f16x8 af[4], bf[4];
#pragma unroll
            for (int mt = 0; mt < 4; mt++)
                af[mt] = *(const f16x8*)&Ast[(wr * 64 + mt * 16 + lr) * 72 +
                                             ks * 32 + 8 * lg];
#pragma unroll
            for (int vt = 0; vt < 4; vt++)
                bf[vt] = *(const f16x8*)&Bw[(wc * 64 + vt * 16 + lr) * 72 +
                                            ks * 32 + 8 * lg];
#pragma unroll
            for (int mt = 0; mt < 4; mt++)
#pragma unroll
                for (int vt = 0; vt < 4; vt++)
                    acc[mt][vt] = MFMA16(af[mt], bf[vt], acc[mt][vt]);
        }
    }

    float bias[4];
#pragma unroll
    for (int vt = 0; vt < 4; vt++)
        bias[vt] = cb[bn * 128 + wc * 64 + vt * 16 + lr];

#pragma unroll
    for (int mt = 0; mt < 4; mt++) {
#pragma unroll
        for (int i = 0; i < 4; i++) {
            int m = bm * 256 + wr * 64 + mt * 16 + 4 * lg + i;
            int bb = m & 3, ss = m >> 2;
            float* orow = out + (size_t)(bb * S_LEN + ss) * NV + bn * 128 + wc * 64;
#pragma unroll
            for (int vt = 0; vt < 4; vt++)
                orow[vt * 16 + lr] = acc[mt][vt][i] + bias[vt];
        }
    }
}

// ---------------------------------------------------------------------------
extern "C" void kernel_launch(void* const* d_in, const int* in_sizes, int n_in,
                              void* d_out, int out_size, void* d_ws, size_t ws_size,
                              hipStream_t stream) {
    (void)in_sizes; (void)n_in; (void)out_size; (void)ws_size;

    const int*   x   = (const int*)d_in[0];
    const float* emb = (const float*)d_in[1];
    const float* a   = (const float*)d_in[2];
    const float* bm  = (const float*)d_in[3];
    const float* cw  = (const float*)d_in[4];
    const float* cb  = (const float*)d_in[5];
    float* out = (float*)d_out;

    char* ws = (char*)d_ws;
    f16* u16 = (f16*)(ws);
    u64* Xllc = (u64*)(ws + (4u << 20));
    u64* Xl   = (u64*)(ws + (8u << 20));
    f16* bT16 = (f16*)(ws + (12u << 20));
    unsigned* ctrl = (unsigned*)(ws + (12u << 20) + (512u << 10));

    hipFuncSetAttribute(reinterpret_cast<const void*>(fused_kernel),
                        hipFuncAttributeMaxDynamicSharedMemorySize,
                        FUSED_LDS);

    transpose512_f16_kernel<<<1024, 256, 0, stream>>>(bm, bT16, Xllc, Xl, ctrl);
    embu_kernel<<<64, 256, 0, stream>>>(x, emb, bT16, u16);
    fused_kernel<<<NCAND + 16 * 250, 512, FUSED_LDS, stream>>>(
        a, u16, cw, cb, Xllc, Xl, ctrl, out);
}

// Round 9
// 1422.192 us; speedup vs baseline: 4.3166x; 4.3166x over previous
//
#include <hip/hip_runtime.h>
#include <hip/hip_fp16.h>

typedef _Float16 f16;
typedef _Float16 f16x8 __attribute__((ext_vector_type(8)));
typedef _Float16 f16x4 __attribute__((ext_vector_type(4)));
typedef float f32x4v __attribute__((ext_vector_type(4)));
typedef unsigned long long u64;

#define S_LEN 1024
#define NS 512
#define NV 32000
#define NW 8          // scan workers (CUs); each owns 64 n-columns
#define SENT 0x7C007C007C007C00ULL   // 4x f16 +inf: unreachable for tanh output
#define FUSED_LDS 98304              // >80KB -> exactly 1 block/CU

#define MFMA16(a, b, c) __builtin_amdgcn_mfma_f32_16x16x32_f16((a), (b), (c), 0, 0, 0)

// ---------------------------------------------------------------------------
// ws layout:
//   u16   : [1024][512][4] f16  at 0      (4 MB)   u[s][n][b]  (batch-packed)
//   X     : u64[1024][512]      at 4 MB   (4 MB)   state record + exchange
//   bT16  : [512][512]     f16  at 8 MB   (512 KB)
// ---------------------------------------------------------------------------

// transpose b -> f16, and refill X with sentinel (every launch; graph-safe)
__global__ __launch_bounds__(256) void transpose512_f16_kernel(
        const float* __restrict__ src, f16* __restrict__ dstT,
        u64* __restrict__ X) {
    int idx = blockIdx.x * 256 + threadIdx.x;   // 0..262143
    X[idx] = SENT;
    X[idx + 262144] = SENT;
    int r = idx >> 9;
    int c = idx & 511;
    dstT[c * 512 + r] = (f16)src[idx];
}

// ---------------------------------------------------------------------------
// embed + input projection: u[m][n] = sum_e emb[x[m]][e] * b[e][n], m = s*4+b
// ---------------------------------------------------------------------------
__global__ __launch_bounds__(256) void embu_kernel(
        const int* __restrict__ x, const float* __restrict__ emb,
        const f16* __restrict__ bT, f16* __restrict__ u16) {
    __shared__ f16 embA[64 * 40];
    __shared__ f16 Bt[512 * 40];
    __shared__ int xi[64];

    int t = threadIdx.x;
    int wg = blockIdx.x;
    if (t < 64) {
        int m = wg * 64 + t;
        int bb = m & 3, ss = m >> 2;
        xi[t] = x[bb * S_LEN + ss];
    }
    __syncthreads();

    int wv = t >> 6, l = t & 63, lr = l & 15, lg = l >> 4;

    f32x4v acc[32];
#pragma unroll
    for (int i = 0; i < 32; i++) acc[i] = (f32x4v){0.f, 0.f, 0.f, 0.f};

    for (int kc = 0; kc < 512; kc += 32) {
        __syncthreads();
        {
            int tk = t >> 2, c0 = (t & 3) * 8;
            const float* src = emb + (size_t)xi[tk] * NS + kc + c0;
            float4 v0 = *(const float4*)src;
            float4 v1 = *(const float4*)(src + 4);
            f16x8 h;
            h[0] = (f16)v0.x; h[1] = (f16)v0.y; h[2] = (f16)v0.z; h[3] = (f16)v0.w;
            h[4] = (f16)v1.x; h[5] = (f16)v1.y; h[6] = (f16)v1.z; h[7] = (f16)v1.w;
            *(f16x8*)&embA[tk * 40 + c0] = h;
        }
        {
            int c0 = (t & 3) * 8;
            int n0 = t >> 2;
#pragma unroll
            for (int rr = 0; rr < 8; rr++) {
                int n = rr * 64 + n0;
                f16x8 v = *(const f16x8*)&bT[n * 512 + kc + c0];
                *(f16x8*)&Bt[n * 40 + c0] = v;
            }
        }
        __syncthreads();

        f16x8 af = *(const f16x8*)&embA[(wv * 16 + lr) * 40 + 8 * lg];
#pragma unroll
        for (int vt = 0; vt < 32; vt++) {
            f16x8 bf = *(const f16x8*)&Bt[(vt * 16 + lr) * 40 + 8 * lg];
            acc[vt] = MFMA16(af, bf, acc[vt]);
        }
    }

    int m0 = wg * 64 + wv * 16 + 4 * lg;
    int ss = m0 >> 2;
#pragma unroll
    for (int vt = 0; vt < 32; vt++) {
        int n = vt * 16 + lr;
        f16x4 h;
#pragma unroll
        for (int i = 0; i < 4; i++) h[i] = (f16)acc[vt][i];
        *(f16x4*)&u16[((size_t)ss * NS + n) * 4] = h;
    }
}

// ---------------------------------------------------------------------------
// FUSED scan + readout.
//   blocks 0..7     : scan. Role-split: waves 0-3 compute (one 16-col MFMA
//                     tile each), waves 4-7 dedicated gather (poll X from
//                     step start -> detection overlaps producer compute).
//   blocks 8..4007  : readout tiles (canary gate + per-element sentinel poll)
// 96 KB dynamic LDS -> 1 block/CU.
// ---------------------------------------------------------------------------
__global__ __launch_bounds__(512) void fused_kernel(
        const float* __restrict__ a, const f16* __restrict__ u16,
        const float* __restrict__ cw, const float* __restrict__ cb,
        u64* __restrict__ X, float* __restrict__ out) {
    extern __shared__ char smem[];
    int t = threadIdx.x;
    int bid = blockIdx.x;
    int w = t >> 6, l = t & 63, lr = l & 15, lg = l >> 4;

    if (bid < NW) {
        // ================= scan =================
        f16* Sb = (f16*)smem;               // [2][4][544] f16
        int r = bid;

        for (int i = t; i < 2 * 4 * 544; i += 512) Sb[i] = (f16)0.f;

        if (w < 4) {
            // ---------- compute wave: n-tile at r*64 + w*16 ----------
            int col = r * 64 + w * 16 + lr;

            f16x8 afr[16];
#pragma unroll
            for (int ks = 0; ks < 16; ks++) {
                f16x8 h;
#pragma unroll
                for (int j = 0; j < 8; j++)
                    h[j] = (f16)a[(size_t)(ks * 32 + 8 * lg + j) * NS + col];
                afr[ks] = h;
            }

            f16x4 upf = *(const f16x4*)&u16[(size_t)col * 4];

            __syncthreads();

#pragma unroll 1
            for (int s = 0; s < S_LEN; s++) {
                int cur = s & 1, nxt = cur ^ 1;

                f32x4v acca, accb;
                acca[0] = (float)upf[0]; acca[1] = (float)upf[1];
                acca[2] = (float)upf[2]; acca[3] = (float)upf[3];
                accb = (f32x4v){0.f, 0.f, 0.f, 0.f};

                {
                    int sn = (s + 1 < S_LEN) ? s + 1 : S_LEN - 1;
                    upf = *(const f16x4*)&u16[((size_t)sn * NS + col) * 4];
                }

                const char* sb = (const char*)Sb + cur * 4352 +
                                 (lr & 3) * 1088 + lg * 16;
#pragma unroll
                for (int ks = 0; ks < 16; ks += 2) {
                    f16x8 s0 = *(const f16x8*)(sb + ks * 64);
                    f16x8 s1 = *(const f16x8*)(sb + ks * 64 + 64);
                    acca = MFMA16(s0, afr[ks], acca);
                    accb = MFMA16(s1, afr[ks + 1], accb);
                }

                if (lg == 0) {
                    union { u64 u; f16 h[4]; } pk;
#pragma unroll
                    for (int i = 0; i < 4; i++) {
                        float y = acca[i] + accb[i];
                        float e = __expf(2.0f * y);
                        float rc = __builtin_amdgcn_rcpf(e + 1.0f);
                        y = __builtin_fmaf(-2.0f, rc, 1.0f);   // tanh
                        pk.h[i] = (f16)y;
                    }
                    __hip_atomic_store(&X[(size_t)s * NS + col], pk.u,
                                       __ATOMIC_RELAXED,
                                       __HIP_MEMORY_SCOPE_AGENT);
#pragma unroll
                    for (int i = 0; i < 4; i++)
                        Sb[nxt * 2176 + i * 544 + col] = pk.h[i];
                }

                if (s == S_LEN - 1) break;

                asm volatile("s_waitcnt lgkmcnt(0)" ::: "memory");
                __builtin_amdgcn_s_barrier();
                __builtin_amdgcn_sched_barrier(0);
            }
        } else {
            // ---------- gather wave: poll remote cols from step start ----
            int i0 = (w - 4) * 64 + l;                 // 0..255
            int col0 = (i0 < r * 64) ? i0 : i0 + 64;
            int i1 = i0 + 256;                         // 256..511
            int col1 = (i1 < 448) ? ((i1 < r * 64) ? i1 : i1 + 64) : -1;

            __syncthreads();

#pragma unroll 1
            for (int s = 0; s < S_LEN - 1; s++) {
                int nxt = (s & 1) ^ 1;

                u64 v0 = SENT;
                u64 v1 = (col1 >= 0) ? SENT : 0ULL;
                const u64* p0 = &X[(size_t)s * NS + col0];
                const u64* p1 = &X[(size_t)s * NS + (col1 >= 0 ? col1 : 0)];
                while (v0 == SENT || v1 == SENT) {
                    if (v0 == SENT)
                        v0 = __hip_atomic_load(p0, __ATOMIC_RELAXED,
                                               __HIP_MEMORY_SCOPE_AGENT);
                    if (v1 == SENT)
                        v1 = __hip_atomic_load(p1, __ATOMIC_RELAXED,
                                               __HIP_MEMORY_SCOPE_AGENT);
                }

                union { u64 u; f16 h[4]; } pk;
                pk.u = v0;
#pragma unroll
                for (int i = 0; i < 4; i++)
                    Sb[nxt * 2176 + i * 544 + col0] = pk.h[i];
                if (col1 >= 0) {
                    pk.u = v1;
#pragma unroll
                    for (int i = 0; i < 4; i++)
                        Sb[nxt * 2176 + i * 544 + col1] = pk.h[i];
                }

                asm volatile("s_waitcnt lgkmcnt(0)" ::: "memory");
                __builtin_amdgcn_s_barrier();
                __builtin_amdgcn_sched_barrier(0);
            }
        }
        return;
    }

    // ================= readout =================
    f16* Ast = (f16*)smem;                 // [256][72]
    f16* Bw = (f16*)(smem + 256 * 72 * 2); // [128][72]

    int idx = bid - NW;
    int bm = idx / 250;      // bm-major: early blocks handle early s
    int bn = idx % 250;
    int s0 = bm * 64;

    if (t == 0) {
        int sc = (bm == 15) ? (S_LEN - 1) : (s0 + 64);
        while (__hip_atomic_load(&X[(size_t)sc * NS], __ATOMIC_RELAXED,
                                 __HIP_MEMORY_SCOPE_AGENT) == SENT)
            __builtin_amdgcn_s_sleep(16);
    }
    __syncthreads();

    int wr = w >> 1, wc = w & 1;

    f32x4v acc[4][4];
#pragma unroll
    for (int i = 0; i < 4; i++)
#pragma unroll
        for (int j = 0; j < 4; j++) acc[i][j] = (f32x4v){0.f, 0.f, 0.f, 0.f};

    for (int kc = 0; kc < 512; kc += 64) {
        __syncthreads();
        // stage A from X: 64 s x 64 cols of u64; per-element sentinel poll
        {
            int srel = t >> 3;
            int ck = (t & 7) * 8;
            const u64* xs = &X[(size_t)(s0 + srel) * NS + kc + ck];
            u64 v[8];
#pragma unroll
            for (int j = 0; j < 8; j++)
                v[j] = __hip_atomic_load(&xs[j], __ATOMIC_RELAXED,
                                         __HIP_MEMORY_SCOPE_AGENT);
#pragma unroll
            for (int j = 0; j < 8; j++)
                while (v[j] == SENT)
                    v[j] = __hip_atomic_load(&xs[j], __ATOMIC_RELAXED,
                                             __HIP_MEMORY_SCOPE_AGENT);
#pragma unroll
            for (int j = 0; j < 8; j++) {
                union { u64 u; f16 h[4]; } pk;
                pk.u = v[j];
#pragma unroll
                for (int b = 0; b < 4; b++)
                    Ast[(srel * 4 + b) * 72 + ck + j] = pk.h[b];
            }
        }
#pragma unroll
        for (int q = 0; q < 4; q++) {
            int i2 = q * 512 + t;
            int row = i2 >> 4;
            int c0 = (i2 & 15) * 4;
            float4 v = *(const float4*)&cw[(size_t)(bn * 128 + row) * NS + kc + c0];
            f16x4 h;
            h[0] = (f16)v.x; h[1] = (f16)v.y; h[2] = (f16)v.z; h[3] = (f16)v.w;
            *(f16x4*)&Bw[row * 72 + c0] = h;
        }
        __syncthreads();

#pragma unroll
        for (int ks = 0; ks < 2; ks++) {
            f16x8 af[4], bf[4];
#pragma unroll
            for (int mt = 0; mt < 4; mt++)
                af[mt] = *(const f16x8*)&Ast[(wr * 64 + mt * 16 + lr) * 72 +
                                             ks * 32 + 8 * lg];
#pragma unroll
            for (int vt = 0; vt < 4; vt++)
                bf[vt] = *(const f16x8*)&Bw[(wc * 64 + vt * 16 + lr) * 72 +
                                            ks * 32 + 8 * lg];
#pragma unroll
            for (int mt = 0; mt < 4; mt++)
#pragma unroll
                for (int vt = 0; vt < 4; vt++)
                    acc[mt][vt] = MFMA16(af[mt], bf[vt], acc[mt][vt]);
        }
    }

    float bias[4];
#pragma unroll
    for (int vt = 0; vt < 4; vt++)
        bias[vt] = cb[bn * 128 + wc * 64 + vt * 16 + lr];

#pragma unroll
    for (int mt = 0; mt < 4; mt++) {
#pragma unroll
        for (int i = 0; i < 4; i++) {
            int m = bm * 256 + wr * 64 + mt * 16 + 4 * lg + i;
            int bb = m & 3, ss = m >> 2;
            float* orow = out + (size_t)(bb * S_LEN + ss) * NV + bn * 128 + wc * 64;
#pragma unroll
            for (int vt = 0; vt < 4; vt++)
                orow[vt * 16 + lr] = acc[mt][vt][i] + bias[vt];
        }
    }
}

// ---------------------------------------------------------------------------
extern "C" void kernel_launch(void* const* d_in, const int* in_sizes, int n_in,
                              void* d_out, int out_size, void* d_ws, size_t ws_size,
                              hipStream_t stream) {
    (void)in_sizes; (void)n_in; (void)out_size; (void)ws_size;

    const int*   x   = (const int*)d_in[0];
    const float* emb = (const float*)d_in[1];
    const float* a   = (const float*)d_in[2];
    const float* bm  = (const float*)d_in[3];
    const float* cw  = (const float*)d_in[4];
    const float* cb  = (const float*)d_in[5];
    float* out = (float*)d_out;

    char* ws = (char*)d_ws;
    f16* u16 = (f16*)(ws);
    u64* X   = (u64*)(ws + (4u << 20));
    f16* bT16 = (f16*)(ws + (8u << 20));

    hipFuncSetAttribute(reinterpret_cast<const void*>(fused_kernel),
                        hipFuncAttributeMaxDynamicSharedMemorySize,
                        FUSED_LDS);

    transpose512_f16_kernel<<<1024, 256, 0, stream>>>(bm, bT16, X);
    embu_kernel<<<64, 256, 0, stream>>>(x, emb, bT16, u16);
    fused_kernel<<<NW + 16 * 250, 512, FUSED_LDS, stream>>>(
        a, u16, cw, cb, X, out);
}